// Round 2
// baseline (1371.740 us; speedup 1.0000x reference)
//
#include <hip/hip_runtime.h>

// SegmentCSR sum, V3: balanced row-sweep + atomic boundary fixup.
//
// Round-1 lesson: wave-per-segment (65536 variable-lifetime waves, data-
// dependent trip counts) sits at ~1.8 TB/s regardless of per-wave ILP --
// the structure, not the schedule, is the bottleneck. V3 assigns each wave
// a FIXED 128-row range of x (uniform lifetime, segment-independent load
// schedule), finds its starting segment via binary search on indptr
// (256 KB, L2-resident), and emits per-segment pieces:
//   - segment fully inside the range  -> plain store
//   - segment crossing a range edge   -> atomicAdd (<=2 per wave)
//   - empty segments                  -> covered by prezero pass
// Reads: one linear sweep of x (1.07 GB). Writes: 33.5 MB prezero +
// 33.5 MB results (+ ~4M scalar f32 atomics).

#define NSEG  65536
#define TOTAL 2097152
#define RPW   128          // rows per wave (fixed)
#define UNR   8            // rows in flight per wave

typedef float f32x2 __attribute__((ext_vector_type(2)));
typedef float f32x4 __attribute__((ext_vector_type(4)));

__global__ __launch_bounds__(256) void zero_out_kernel(f32x4* __restrict__ out4)
{
    const size_t i = (size_t)blockIdx.x * 256 + threadIdx.x; // 8192 blocks
    f32x4 z = {0.f, 0.f, 0.f, 0.f};
    __builtin_nontemporal_store(z, out4 + i);
}

__global__ __launch_bounds__(256) void segcsr_sweep(
    const f32x2* __restrict__ x,      // [TOTAL * 64] float2 (row = 64 float2)
    const int*   __restrict__ indptr, // [NSEG + 1]
    float*       __restrict__ out)    // [NSEG * 128]
{
    // Wave-uniform scalars: readfirstlane so indptr loads/compares go scalar.
    const int wid  = __builtin_amdgcn_readfirstlane((blockIdx.x << 2) + (threadIdx.x >> 6));
    const int lane = threadIdx.x & 63;
    const int r0 = wid * RPW;
    const int r1 = r0 + RPW;

    // Binary search: s with indptr[s] <= r0 < indptr[s+1].
    // (indptr[0]=0, indptr[NSEG]=TOTAL>r0 -> well-defined; picks the LAST
    // segment starting at r0, skipping empties that end there.)
    int lo = 0, hi = NSEG;
    while (hi - lo > 1) {
        const int mid = (lo + hi) >> 1;
        if (indptr[mid] <= r0) lo = mid; else hi = mid;
    }
    int s        = lo;
    int segBegin = indptr[s];
    int segEnd   = indptr[s + 1];

    float ax = 0.f, ay = 0.f;
    int lastFlush = r0;

    for (int base = r0; base < r1; base += UNR) {
        f32x2 v[UNR];
#pragma unroll
        for (int j = 0; j < UNR; ++j)
            v[j] = __builtin_nontemporal_load(&x[(size_t)(base + j) * 64 + lane]);
#pragma unroll
        for (int j = 0; j < UNR; ++j) {
            ax += v[j].x;
            ay += v[j].y;
            const int rr = base + j + 1;   // boundary after row base+j
            if (rr == segEnd) {
                float* o = out + (size_t)s * 128 + lane * 2;
                if (segBegin >= r0) {       // piece == whole segment
                    o[0] = ax; o[1] = ay;
                } else {                    // segment started before our range
                    atomicAdd(o,     ax);
                    atomicAdd(o + 1, ay);
                }
                ax = 0.f; ay = 0.f;
                lastFlush = rr;
                if (rr < TOTAL) {
                    // advance to the segment containing row rr, skipping
                    // empties (they stay prezeroed = correct)
                    do { s++; } while (indptr[s + 1] <= rr);
                    segBegin = rr;          // chain of empties all begin at rr
                    segEnd   = indptr[s + 1];
                }
            }
        }
    }

    // Pending partial piece at range end (segment continues past r1).
    if (lastFlush < r1) {
        float* o = out + (size_t)s * 128 + lane * 2;
        atomicAdd(o,     ax);
        atomicAdd(o + 1, ay);
    }
}

extern "C" void kernel_launch(void* const* d_in, const int* in_sizes, int n_in,
                              void* d_out, int out_size, void* d_ws, size_t ws_size,
                              hipStream_t stream) {
    const f32x2* x      = (const f32x2*)d_in[0];
    const int*   indptr = (const int*)d_in[1];
    float*       out    = (float*)d_out;

    // Pass 1: zero the output (empty segments + atomic accumulation base).
    // NSEG*128 floats = 2,097,152 float4 -> 8192 blocks x 256 threads.
    zero_out_kernel<<<dim3(8192), dim3(256), 0, stream>>>((f32x4*)out);

    // Pass 2: balanced sweep. TOTAL/RPW = 16384 waves -> 4096 blocks x 4 waves.
    segcsr_sweep<<<dim3(TOTAL / RPW / 4), dim3(256), 0, stream>>>(x, indptr, out);
}

// Round 3
// 1329.835 us; speedup vs baseline: 1.0315x; 1.0315x over previous
//
#include <hip/hip_runtime.h>

// SegmentCSR sum, V4: balanced row-sweep, float4 lanes, pair-boundary fixup.
//
// Evidence so far: three disjoint structures all land at dur 1306-1371 us.
// Remaining discriminator: bytes per VMEM instruction. V4 reads x with
// global_load_dwordx4 (64 lanes x 16 B = 1 KiB = 2 rows per instruction,
// 8 loads = 8 KiB in flight per wave), 256 rows per wave -> exactly 8192
// uniform-lifetime waves (256 CU x 32 waves). Segment boundaries:
//   - boundary between row-pairs: flush (shfl-fold halves) after add
//   - boundary mid-pair: rh0 adds its row, flush, rh1 adds its row
//   - piece == whole segment -> plain store; range-crossing -> atomicAdd
//   - empty segments -> prezero pass
// All flush branches are wave-uniform (segEnd is scalar).

#define NSEG  65536
#define TOTAL 2097152
#define RPW   256          // rows per wave (fixed, uniform lifetime)
#define UNRP  8            // row-PAIRS in flight per wave (16 rows, 8 KiB)

typedef float f32x4 __attribute__((ext_vector_type(4)));

__global__ __launch_bounds__(256) void zero_out_kernel(f32x4* __restrict__ out4)
{
    const size_t i = (size_t)blockIdx.x * 256 + threadIdx.x; // 8192 blocks
    f32x4 z = {0.f, 0.f, 0.f, 0.f};
    __builtin_nontemporal_store(z, out4 + i);
}

__global__ __launch_bounds__(256) void segcsr_sweep(
    const f32x4* __restrict__ x,      // [TOTAL * 32] float4 (row = 32 float4)
    const int*   __restrict__ indptr, // [NSEG + 1]
    float*       __restrict__ out)    // [NSEG * 128]
{
    const int wid  = __builtin_amdgcn_readfirstlane((blockIdx.x << 2) + (threadIdx.x >> 6));
    const int lane = threadIdx.x & 63;
    const int c    = lane & 31;   // float4 column within a row
    const int rh   = lane >> 5;   // row phase within a pair: 0 or 1
    const int r0   = wid * RPW;
    const int r1   = r0 + RPW;

    // Binary search: last s with indptr[s] <= r0 (so indptr[s+1] > r0).
    int lo = 0, hi = NSEG;
    while (hi - lo > 1) {
        const int mid = (lo + hi) >> 1;
        if (indptr[mid] <= r0) lo = mid; else hi = mid;
    }
    int s         = lo;
    int segBegin  = indptr[s];
    int segEnd    = indptr[s + 1];
    int lastFlush = r0;

    f32x4 acc = {0.f, 0.f, 0.f, 0.f};

    // Flush piece [lastFlush, rr) of segment s; advance to segment containing rr.
    auto FLUSH = [&](int rr) {
        float tx = acc.x + __shfl_down(acc.x, 32);
        float ty = acc.y + __shfl_down(acc.y, 32);
        float tz = acc.z + __shfl_down(acc.z, 32);
        float tw = acc.w + __shfl_down(acc.w, 32);
        if (rh == 0) {
            float* o = out + (size_t)s * 128 + c * 4;
            if (segBegin >= r0) {            // piece == whole segment: exclusive
                f32x4 t = {tx, ty, tz, tw};
                __builtin_nontemporal_store(t, (f32x4*)o);
            } else {                         // segment started before our range
                atomicAdd(o,     tx);
                atomicAdd(o + 1, ty);
                atomicAdd(o + 2, tz);
                atomicAdd(o + 3, tw);
            }
        }
        acc.x = 0.f; acc.y = 0.f; acc.z = 0.f; acc.w = 0.f;
        lastFlush = rr;
        if (rr < r1) {                       // find segment containing row rr
            do { s++; } while (indptr[s + 1] <= rr);  // skip empties (stay prezeroed)
            segBegin = rr;                   // previous segment ended at rr
            segEnd   = indptr[s + 1];
        }
    };

    for (int base = r0; base < r1; base += 2 * UNRP) {
        f32x4 v[UNRP];
#pragma unroll
        for (int j = 0; j < UNRP; ++j)
            v[j] = __builtin_nontemporal_load(&x[(size_t)(base + 2 * j + rh) * 32 + c]);
#pragma unroll
        for (int j = 0; j < UNRP; ++j) {
            const int b   = base + 2 * j;
            const int rr1 = b + 1;           // boundary after pair's first row
            const int rr2 = b + 2;           // boundary after pair's second row
            if (segEnd == rr1) {             // wave-uniform
                if (rh == 0) acc += v[j];    // first row ends the segment
                FLUSH(rr1);
                if (rh == 1) acc += v[j];    // second row starts the next one
            } else {
                acc += v[j];
            }
            if (segEnd == rr2) {             // wave-uniform
                FLUSH(rr2);
            }
        }
    }

    // Pending piece [lastFlush, r1): segment continues past r1 -> atomic.
    if (lastFlush < r1) {
        float tx = acc.x + __shfl_down(acc.x, 32);
        float ty = acc.y + __shfl_down(acc.y, 32);
        float tz = acc.z + __shfl_down(acc.z, 32);
        float tw = acc.w + __shfl_down(acc.w, 32);
        if (rh == 0) {
            float* o = out + (size_t)s * 128 + c * 4;
            atomicAdd(o,     tx);
            atomicAdd(o + 1, ty);
            atomicAdd(o + 2, tz);
            atomicAdd(o + 3, tw);
        }
    }
}

extern "C" void kernel_launch(void* const* d_in, const int* in_sizes, int n_in,
                              void* d_out, int out_size, void* d_ws, size_t ws_size,
                              hipStream_t stream) {
    const f32x4* x      = (const f32x4*)d_in[0];
    const int*   indptr = (const int*)d_in[1];
    float*       out    = (float*)d_out;

    // Pass 1: zero output (empty segments + atomic base). 2M float4 / 256.
    zero_out_kernel<<<dim3(8192), dim3(256), 0, stream>>>((f32x4*)out);

    // Pass 2: TOTAL/RPW = 8192 waves -> 2048 blocks x 4 waves. Exactly fills
    // 256 CUs x 32 waves, uniform lifetime, one contiguous 128 KiB range each.
    segcsr_sweep<<<dim3(TOTAL / RPW / 4), dim3(256), 0, stream>>>(x, indptr, out);
}